// Round 10
// baseline (1025.057 us; speedup 1.0000x reference)
//
#include <hip/hip_runtime.h>
#include <hip/hip_bf16.h>
#include <math.h>

typedef __hip_bfloat16 bf16;

#define DEV static __device__ __forceinline__

DEV float geluf(float x){ return 0.5f*x*(1.0f + erff(x*0.70710678118654752f)); }
DEV float sigmf(float x){ return 1.0f/(1.0f + __expf(-x)); }
DEV float softplusf(float x){ return (x > 15.f) ? x : log1pf(__expf(x)); }
DEV float tanhfast(float x){ float e = __expf(2.f*x); return fmaf(-2.f, 1.f/(e+1.f), 1.f); }

typedef __attribute__((ext_vector_type(8))) short v8s;   // 8 bf16 (4 VGPRs)
typedef __attribute__((ext_vector_type(4))) float v4f;   // 4 fp32 acc
typedef _Float16 f16;
typedef f16 h2 __attribute__((ext_vector_type(2)));
typedef f16 f16x8 __attribute__((ext_vector_type(8)));   // 16B chunk (4 h2)
typedef unsigned u32x4 __attribute__((ext_vector_type(4)));

DEV float dot2f(h2 a, h2 b, float c){
#if __has_builtin(__builtin_amdgcn_fdot2)
  return __builtin_amdgcn_fdot2(a, b, c, false);
#else
  return fmaf((float)a.y, (float)b.y, fmaf((float)a.x, (float)b.x, c));
#endif
}

DEV h2 geth2(f16x8 v, int j){ h2 r; r.x = v[2*j]; r.y = v[2*j+1]; return r; }

// LDS-only barrier (lstm path): orders ds ops, leaves global loads in flight.
DEV void lds_barrier(){
  asm volatile("s_waitcnt lgkmcnt(0)" ::: "memory");
  __builtin_amdgcn_s_barrier();
  __builtin_amdgcn_sched_barrier(0);
}

DEV void write_feat7(float* fp, float v){
  fp[0]=v;
  fp[1]=sinf(v); fp[2]=sinf(2.f*v); fp[3]=sinf(4.f*v);
  fp[4]=cosf(v); fp[5]=cosf(2.f*v); fp[6]=cosf(4.f*v);
}

// ---------------- workspace layout (float offsets) ----------------
enum : size_t {
  OFF_W1F   = 0,        // 2048  folded enc conv1 weights (256x8)
  OFF_B1F   = 2048,     // 256
  OFF_S2E   = 2304,     // 64
  OFF_B2E   = 2368,     // 64
  OFF_WIHT  = 2432,     // 32768 w_ih^T (64x512)
  OFF_BIASG = 35200,    // 512   b_ih+b_hh
  OFF_WHHT  = 35712,    // whh packed f16 pairs, GATE-major: h2[512][64]
  OFF_EPI1S = 101248,   // 128
  OFF_EPI1B = 101376,   // 128
  OFF_EPI2S = 101504,   // 256
  OFF_EPI2B = 101760,   // 256
  OFF_EPI3S = 102016,   // 128
  OFF_EPI3B = 102144,   // 128
  OFF_WE2B  = 102272,   // 262144 floats = 524288 bf16: we2 repacked [o][e][f]
  OFF_XSRC  = 364416,   // 524288 (B,T,64)
  OFF_GX    = 888704,   // 4194304 (B,T,512); reused as kanp(mc/sc) partials after lstm
  OFF_HSEQ  = 5083008,  // 1048576 (B,T,128)
  OFF_PCOL  = 7180160,  // 8192
  OFF_CCOL  = 7188352,  // 8192
  OFF_CUTS  = 7196544,  // 32 (int)
  OFF_LAST  = 7196576,  // 4096
  OFF_FEATA = 7204768,  // 28672 (B,128,7)
  OFF_FEATB = 7249824,  // 57344 (B,256,7)
  OFF_WC3P  = 7315360,  // 131072 wc3 padded [128][256][4]
  OFF_WC2P  = 7446432,  // 262144 wc2 padded [256][128][8]
  OFF_KP    = 7708576,  // 32768 kan partials: mu at +0, sd at +16384
  OFF_B2S   = 7741344,  // 522: per-kan sum_i B2: mu+0,std+128,muc+256,stdc+384,fc+512
  OFF_X2F   = 7839648,  // 4096
  OFF_FEATC = 7851936,  // 57344
  WS_FLOATS = 7909280
};

// ---------------- prep: fold BN, pack LSTM weights, repack we2, pad wc2/wc3, B2 sums ----
__global__ __launch_bounds__(256) void prep_kernel(
    const float* we1, const float* be1,
    const float* e1g, const float* e1b, const float* e1m, const float* e1v,
    const float* we2, const float* be2, const float* e2g, const float* e2b, const float* e2m, const float* e2v,
    const float* wih, const float* whh, const float* bih, const float* bhh,
    const float* bc1, const float* c1g, const float* c1b, const float* c1m, const float* c1v,
    const float* bc2, const float* c2g, const float* c2b, const float* c2m, const float* c2v,
    const float* bc3, const float* c3g, const float* c3b, const float* c3m, const float* c3v,
    const float* muB2, const float* sdB2, const float* mcB2, const float* scB2, const float* fcB2,
    const float* wc2, const float* wc3,
    float* ws)
{
  int idx = blockIdx.x*256 + threadIdx.x;
  if(idx < 2048){
    int o = idx>>3;
    float s = e1g[o] * rsqrtf(e1v[o] + 1e-5f);
    ws[OFF_W1F + idx] = we1[idx] * s;
  } else if(idx < 2304){
    int o = idx - 2048;
    float s = e1g[o] * rsqrtf(e1v[o] + 1e-5f);
    ws[OFF_B1F + o] = s*(be1[o] - e1m[o]) + e1b[o];
  } else if(idx < 2368){
    int e = idx - 2304;
    float s = e2g[e] * rsqrtf(e2v[e] + 1e-5f);
    ws[OFF_S2E + e] = s;
    ws[OFF_B2E + e] = s*(be2[e] - e2m[e]) + e2b[e];
  } else if(idx < 35136){
    int q = idx - 2368; int e = q>>9, g = q&511;
    ws[OFF_WIHT + q] = wih[g*64 + e];
  } else if(idx < 35648){
    int g = idx - 35136;
    ws[OFF_BIASG + g] = bih[g] + bhh[g];
  } else if(idx < 101184){
    int q = idx - 35648;
    if(q < 32768){
      int k2 = q>>9, g = q&511;
      h2 v;
      v.x = (f16)whh[g*128 + 2*k2];
      v.y = (f16)whh[g*128 + 2*k2 + 1];
      ((h2*)(ws + OFF_WHHT))[g*64 + k2] = v;
    }
  } else if(idx < 101312){
    int o = idx - 101184;
    float s = c1g[o] * rsqrtf(c1v[o] + 1e-3f);
    ws[OFF_EPI1S + o] = s;
    ws[OFF_EPI1B + o] = s*(bc1[o] - c1m[o]) + c1b[o];
  } else if(idx < 101568){
    int o = idx - 101312;
    float s = c2g[o] * rsqrtf(c2v[o] + 1e-3f);
    ws[OFF_EPI2S + o] = s;
    ws[OFF_EPI2B + o] = s*(bc2[o] - c2m[o]) + c2b[o];
  } else if(idx < 101696){
    int o = idx - 101568;
    float s = c3g[o] * rsqrtf(c3v[o] + 1e-3f);
    ws[OFF_EPI3S + o] = s;
    ws[OFF_EPI3B + o] = s*(bc3[o] - c3m[o]) + c3b[o];
  } else if(idx < 625984){
    int q = idx - 101696;
    int o = q >> 11, rem = q & 2047;
    int e = rem >> 5, f = rem & 31;
    bf16* Wr = (bf16*)(ws + OFF_WE2B);
    Wr[q] = __float2bfloat16(we2[(size_t)e*8192 + o*32 + f]);
  } else if(idx < 626112){
    int j = idx - 625984; float s = 0.f;
    for(int i=0;i<128;i++) s += muB2[i*128+j];
    ws[OFF_B2S + j] = s;
  } else if(idx < 626240){
    int j = idx - 626112; float s = 0.f;
    for(int i=0;i<128;i++) s += sdB2[i*128+j];
    ws[OFF_B2S + 128 + j] = s;
  } else if(idx < 626368){
    int j = idx - 626240; float s = 0.f;
    for(int i=0;i<256;i++) s += mcB2[i*128+j];
    ws[OFF_B2S + 256 + j] = s;
  } else if(idx < 626496){
    int j = idx - 626368; float s = 0.f;
    for(int i=0;i<256;i++) s += scB2[i*128+j];
    ws[OFF_B2S + 384 + j] = s;
  } else if(idx < 626506){
    int j = idx - 626496; float s = 0.f;
    for(int i=0;i<256;i++) s += fcB2[i*10+j];
    ws[OFF_B2S + 512 + j] = s;
  } else if(idx < 888650){
    // wc2 pad: [256][128][5] -> [256][128][8] (float4-loadable)
    int q = idx - 626506;
    int o = q >> 10, rem = q & 1023;
    int c = rem >> 3, k = rem & 7;
    ws[OFF_WC2P + q] = (k < 5) ? wc2[(size_t)o*640 + c*5 + k] : 0.f;
  } else if(idx < 1019722){
    // wc3 pad: [128][256][3] -> [128][256][4]
    int q = idx - 888650;
    int o = q >> 10, rem = q & 1023;
    int c = rem >> 2, k = rem & 3;
    ws[OFF_WC3P + q] = (k < 3) ? wc3[(size_t)o*768 + c*3 + k] : 0.f;
  }
}

// ---------------- encoder: conv1(1x8 SAME)+BN+GELU fused into bf16 MFMA GEMM ----------------
__global__ __launch_bounds__(256,1) void encoder_kernel(
    const float* __restrict__ x, const float* __restrict__ w1f, const float* __restrict__ b1f,
    const float* __restrict__ s2e, const float* __restrict__ b2e,
    const bf16* __restrict__ Wr, float* __restrict__ x_src)
{
  __shared__ float xs[39*32];
  __shared__ float w1s[2048];
  __shared__ float b1s[256];
  __shared__ __align__(16) unsigned short At[2][32*136];
  __shared__ __align__(16) unsigned short Bt[2][4*2560];

  int blk = blockIdx.x; int b = blk>>3; int t0 = (blk&7)*32;
  int tid = threadIdx.x;

  for(int i=tid;i<2048;i+=256) w1s[i] = w1f[i];
  b1s[tid] = b1f[tid];
  for(int i=tid;i<39*32;i+=256){
    int r=i>>5, f=i&31; int t=t0-3+r;
    xs[i] = (t>=0 && t<256) ? x[(b*256+t)*32+f] : 0.f;
  }
  __syncthreads();

  int f = tid & 31, tq = tid >> 5;
  int lane = tid & 63, w = tid >> 6;
  int wm = w & 1, wn = w >> 1;
  int m0 = wm*16, n0 = wn*32;
  int l15 = lane & 15, quad = lane >> 4;

  const v8s* Wv = (const v8s*)Wr;

  auto stage = [&](int cc, int buf){
    v8s bw[4];
    #pragma unroll
    for(int i=0;i<4;i++) bw[i] = Wv[cc*1024 + i*256 + tid];
    unsigned short aval[16];
    #pragma unroll
    for(int ol=0;ol<4;ol++){
      int o = cc*4 + ol;
      float wv[8];
      #pragma unroll
      for(int j=0;j<8;j++) wv[j] = w1s[o*8+j];
      float bb = b1s[o];
      #pragma unroll
      for(int i=0;i<4;i++){
        int tl = tq*4 + i;
        float c = bb;
        #pragma unroll
        for(int j=0;j<8;j++) c = fmaf(wv[j], xs[(tl+j)*32+f], c);
        aval[ol*4+i] = ((__hip_bfloat16_raw)__float2bfloat16(geluf(c))).x;
      }
    }
    #pragma unroll
    for(int ol=0;ol<4;ol++){
      #pragma unroll
      for(int i=0;i<4;i++)
        At[buf][(tq*4+i)*136 + ol*32 + f] = aval[ol*4+i];
    }
    #pragma unroll
    for(int i=0;i<4;i++){
      int j = i*256 + tid;
      int ol = j>>8, e = (j&255)>>2, f8 = j&3;
      *(v8s*)&Bt[buf][ol*2560 + e*40 + f8*8] = bw[i];
    }
  };

  stage(0, 0);
  __syncthreads();

  v4f acc0 = {0.f,0.f,0.f,0.f}, acc1 = {0.f,0.f,0.f,0.f};

  for(int c=0;c<64;c++){
    int p = c & 1, q = p ^ 1;
    if(c < 63) stage(c+1, q);
    #pragma unroll
    for(int ol=0;ol<4;ol++){
      v8s av = *(const v8s*)&At[p][(m0+l15)*136 + ol*32 + quad*8];
      v8s b0 = *(const v8s*)&Bt[p][ol*2560 + (n0+l15)*40 + quad*8];
      v8s b1 = *(const v8s*)&Bt[p][ol*2560 + (n0+16+l15)*40 + quad*8];
      acc0 = __builtin_amdgcn_mfma_f32_16x16x32_bf16(av, b0, acc0, 0, 0, 0);
      acc1 = __builtin_amdgcn_mfma_f32_16x16x32_bf16(av, b1, acc1, 0, 0, 0);
    }
    __syncthreads();
  }

  #pragma unroll
  for(int r=0;r<4;r++){
    int t = t0 + m0 + quad*4 + r;
    int e0 = n0 + l15;
    float v0 = geluf(s2e[e0]*acc0[r] + b2e[e0]);
    x_src[((size_t)(b*256+t))*64 + e0] = v0;
    int e1 = e0 + 16;
    float v1 = geluf(s2e[e1]*acc1[r] + b2e[e1]);
    x_src[((size_t)(b*256+t))*64 + e1] = v1;
  }
}

// ---------------- gates_x = x_src @ w_ih^T + bias ----------------
__global__ __launch_bounds__(256) void gates_kernel(
    const float* x_src, const float* wihT, const float* biasg, float* gx)
{
  __shared__ float xsh[32*64];
  int blk = blockIdx.x; int b = blk>>3, t0 = (blk&7)*32;
  int tid = threadIdx.x;
  for(int i=tid;i<2048;i+=256) xsh[i] = x_src[((size_t)b*256+t0)*64 + i];
  __syncthreads();
  int g0 = tid, g1 = tid + 256;
  float acc0[32], acc1[32];
  #pragma unroll
  for(int tt=0;tt<32;tt++){ acc0[tt]=0.f; acc1[tt]=0.f; }
  for(int e=0;e<64;e++){
    float w0 = wihT[e*512+g0], w1 = wihT[e*512+g1];
    #pragma unroll
    for(int tt=0;tt<32;tt++){
      float xv = xsh[tt*64+e];
      acc0[tt] = fmaf(xv, w0, acc0[tt]);
      acc1[tt] = fmaf(xv, w1, acc1[tt]);
    }
  }
  float bg0 = biasg[g0], bg1 = biasg[g1];
  #pragma unroll
  for(int tt=0;tt<32;tt++){
    gx[((size_t)b*256+t0+tt)*512 + g0] = acc0[tt] + bg0;
    gx[((size_t)b*256+t0+tt)*512 + g1] = acc1[tt] + bg1;
  }
}

// ---------------- MEGA kernel: blocks 0-31 = LSTM; 32-63 = conv/SE branch (hidden) -----
#define LSTM_STEP(GI, GF, GG, GO, PR, PW, T)                                 \
  {                                                                          \
    const f16x8* hp = (const f16x8*)&hsh[PR][half*64];                       \
    f16x8 hvv[8];                                                            \
    _Pragma("unroll")                                                        \
    for(int q=0;q<8;q++) hvv[q] = hp[q];                                     \
    float si=0.f, sf=0.f, sg=0.f, so=0.f;                                    \
    _Pragma("unroll")                                                        \
    for(int q=0;q<8;q++){                                                    \
      f16x8 Wi = __builtin_bit_cast(f16x8, wi[q]);                           \
      f16x8 Wf = __builtin_bit_cast(f16x8, wf[q]);                           \
      f16x8 Wg = __builtin_bit_cast(f16x8, wg[q]);                           \
      f16x8 Wo = __builtin_bit_cast(f16x8, wo[q]);                           \
      f16x8 hq = hvv[q];                                                     \
      _Pragma("unroll")                                                      \
      for(int j=0;j<4;j++){                                                  \
        h2 hj = geth2(hq, j);                                                \
        si = dot2f(hj, geth2(Wi,j), si);                                     \
        sf = dot2f(hj, geth2(Wf,j), sf);                                     \
        sg = dot2f(hj, geth2(Wg,j), sg);                                     \
        so = dot2f(hj, geth2(Wo,j), so);                                     \
      }                                                                      \
    }                                                                        \
    si += __shfl_xor(si, 32, 64);                                            \
    sf += __shfl_xor(sf, 32, 64);                                            \
    sg += __shfl_xor(sg, 32, 64);                                            \
    so += __shfl_xor(so, 32, 64);                                            \
    float iv = sigmf(si + (GI));                                             \
    float fv = sigmf(sf + (GF));                                             \
    float gv = tanhfast(sg + (GG));                                          \
    float ov = sigmf(so + (GO));                                             \
    c = fmaf(fv, c, iv*gv);                                                  \
    float h = ov*tanhfast(c);                                                \
    if(half == 0){                                                           \
      hsh[PW][n] = (f16)h;                                                   \
      hseq[((size_t)b*256+(T))*128 + n] = h;                                 \
    }                                                                        \
    lds_barrier();                                                           \
  }

__global__ __launch_bounds__(256)
__attribute__((amdgpu_waves_per_eu(1,1)))
void lstm_conv_kernel(
    const float* __restrict__ gates_x, const float* __restrict__ whh16f, float* __restrict__ hseq,
    const float* __restrict__ x,
    const float* __restrict__ wc1, const float* __restrict__ wc2p, const float* __restrict__ wc3p,
    const float* __restrict__ epi1s, const float* __restrict__ epi1b,
    const float* __restrict__ epi2s, const float* __restrict__ epi2b,
    const float* __restrict__ epi3s, const float* __restrict__ epi3b,
    const float* __restrict__ se1w1, const float* __restrict__ se1w2,
    const float* __restrict__ se2w1, const float* __restrict__ se2w2,
    float* __restrict__ x2f)
{
  __shared__ __align__(16) f16 hsh[2][128];
  __shared__ __align__(16) float bufA[8192];   // conv: x (256x32), later y2 (256x32)
  __shared__ __align__(16) float bufB[4096];   // conv: y1 (128x32)
  __shared__ float msh[256];
  __shared__ float ysh[16];

  int tid = threadIdx.x;
  if(blockIdx.x < 32){
    // ---------------- LSTM path (R7 structure, 177us floor) ----------------
    int b = blockIdx.x;
    int wave = tid >> 6, lane = tid & 63;
    int half = lane >> 5;
    int n = wave*32 + (lane & 31);

    const u32x4* Wp = (const u32x4*)whh16f;
    u32x4 wi[8], wf[8], wg[8], wo[8];
    #pragma unroll
    for(int q=0;q<8;q++){
      wi[q] = Wp[(size_t)(n      )*16 + half*8 + q];
      wf[q] = Wp[(size_t)(n + 128)*16 + half*8 + q];
      wg[q] = Wp[(size_t)(n + 256)*16 + half*8 + q];
      wo[q] = Wp[(size_t)(n + 384)*16 + half*8 + q];
    }
    asm volatile("" :
      "+v"(wi[0]), "+v"(wi[1]), "+v"(wi[2]), "+v"(wi[3]),
      "+v"(wi[4]), "+v"(wi[5]), "+v"(wi[6]), "+v"(wi[7]),
      "+v"(wf[0]), "+v"(wf[1]), "+v"(wf[2]), "+v"(wf[3]),
      "+v"(wf[4]), "+v"(wf[5]), "+v"(wf[6]), "+v"(wf[7]));
    asm volatile("" :
      "+v"(wg[0]), "+v"(wg[1]), "+v"(wg[2]), "+v"(wg[3]),
      "+v"(wg[4]), "+v"(wg[5]), "+v"(wg[6]), "+v"(wg[7]),
      "+v"(wo[0]), "+v"(wo[1]), "+v"(wo[2]), "+v"(wo[3]),
      "+v"(wo[4]), "+v"(wo[5]), "+v"(wo[6]), "+v"(wo[7]));

    if(tid < 128) hsh[0][tid] = (f16)0.f;
    float c = 0.f;
    const float* gx = gates_x + (size_t)b*256*512;
    float i0v = gx[n], f0v = gx[128+n], g0v = gx[256+n], o0v = gx[384+n];
    float i1v = gx[512+n], f1v = gx[512+128+n], g1v = gx[512+256+n], o1v = gx[512+384+n];
    __syncthreads();
    for(int t=0; t<256; t+=2){
      float i2v=0.f,f2v=0.f,g2v=0.f,o2v=0.f,i3v=0.f,f3v=0.f,g3v=0.f,o3v=0.f;
      if(t+2 < 256){
        const float* gp = gx + (size_t)(t+2)*512;
        i2v = gp[n]; f2v = gp[128+n]; g2v = gp[256+n]; o2v = gp[384+n];
      }
      LSTM_STEP(i0v, f0v, g0v, o0v, 0, 1, t);
      if(t+3 < 256){
        const float* gp = gx + (size_t)(t+3)*512;
        i3v = gp[n]; f3v = gp[128+n]; g3v = gp[256+n]; o3v = gp[384+n];
      }
      LSTM_STEP(i1v, f1v, g1v, o1v, 1, 0, t+1);
      i0v=i2v; f0v=f2v; g0v=g2v; o0v=o2v;
      i1v=i3v; f1v=f3v; g1v=g3v; o1v=o3v;
    }
  } else {
    // ---------------- conv branch: one block per batch ----------------
    int cb = blockIdx.x - 32;
    for(int i=tid; i<8192; i+=256) bufA[i] = x[(size_t)cb*8192 + i];
    __syncthreads();

    int wv_ = tid >> 6, ln = tid & 63;
    int lh = wv_ >> 1;                 // waves 0,1: lower 16 l; waves 2,3: upper
    int o  = ((wv_ & 1) << 6) | ln;    // 0..127

    // ---- conv1: CIN=256, K=8, COUT=128; (o, lh) per thread, L=16 ----
    {
      float acc[16];
      #pragma unroll
      for(int j=0;j<16;j++) acc[j]=0.f;
      const float4* wp = (const float4*)(wc1 + (size_t)o*2048);
      if(lh == 0){
        for(int c=0;c<256;c++){
          const float4* rp = (const float4*)&bufA[c*32];
          float4 r0=rp[0], r1=rp[1], r2=rp[2], r3=rp[3];
          float xr[16]={r0.x,r0.y,r0.z,r0.w,r1.x,r1.y,r1.z,r1.w,
                        r2.x,r2.y,r2.z,r2.w,r3.x,r3.y,r3.z,r3.w};
          float4 w0=wp[2*c], w1=wp[2*c+1];
          float wv[8]={w0.x,w0.y,w0.z,w0.w,w1.x,w1.y,w1.z,w1.w};
          #pragma unroll
          for(int j=0;j<16;j++){
            #pragma unroll
            for(int k=0;k<8;k++){
              int idx = j + k - 7;
              if(idx >= 0) acc[j] = fmaf(xr[idx], wv[k], acc[j]);
            }
          }
        }
      } else {
        for(int c=0;c<256;c++){
          const float4* rp = (const float4*)&bufA[c*32];
          float4 r2=rp[2], r3=rp[3], r4=rp[4], r5=rp[5], r6=rp[6], r7=rp[7];
          float xr[24]={r2.x,r2.y,r2.z,r2.w,r3.x,r3.y,r3.z,r3.w,
                        r4.x,r4.y,r4.z,r4.w,r5.x,r5.y,r5.z,r5.w,
                        r6.x,r6.y,r6.z,r6.w,r7.x,r7.y,r7.z,r7.w};  // vals 8..31
          float4 w0=wp[2*c], w1=wp[2*c+1];
          float wv[8]={w0.x,w0.y,w0.z,w0.w,w1.x,w1.y,w1.z,w1.w};
          #pragma unroll
          for(int j=0;j<16;j++){
            #pragma unroll
            for(int k=0;k<8;k++)
              acc[j] = fmaf(xr[j+k+1], wv[k], acc[j]);   // idx = 16+j-7+k = (j+k+1)+8
          }
        }
      }
      float s = epi1s[o], bb = epi1b[o];
      float g[16]; float m = 0.f;
      #pragma unroll
      for(int j=0;j<16;j++){ g[j] = geluf(s*acc[j]+bb); m += g[j]; }
      msh[lh*128 + o] = m;
      __syncthreads();
      if(tid < 8){
        float t2 = 0.f;
        for(int k=0;k<128;k++) t2 = fmaf((msh[k]+msh[128+k])*(1.f/32.f), se1w1[tid*128+k], t2);
        ysh[tid] = fmaxf(t2, 0.f);
      }
      __syncthreads();
      float t2 = 0.f;
      #pragma unroll
      for(int k=0;k<8;k++) t2 = fmaf(ysh[k], se1w2[o*8+k], t2);
      float sc = sigmf(t2);
      #pragma unroll
      for(int j=0;j<16;j++) bufB[o*32 + lh*16 + j] = g[j]*sc;
      __syncthreads();
    }

    // ---- conv2: CIN=128, K=5, COUT=256; o = tid, L=32 ----
    {
      int oc = tid;
      float acc[32];
      #pragma unroll
      for(int j=0;j<32;j++) acc[j]=0.f;
      const float4* wp = (const float4*)(wc2p + (size_t)oc*1024);
      for(int c=0;c<128;c++){
        const float4* rp = (const float4*)&bufB[c*32];
        float4 r0=rp[0],r1=rp[1],r2=rp[2],r3=rp[3],r4=rp[4],r5=rp[5],r6=rp[6],r7=rp[7];
        float xr[32]={r0.x,r0.y,r0.z,r0.w,r1.x,r1.y,r1.z,r1.w,
                      r2.x,r2.y,r2.z,r2.w,r3.x,r3.y,r3.z,r3.w,
                      r4.x,r4.y,r4.z,r4.w,r5.x,r5.y,r5.z,r5.w,
                      r6.x,r6.y,r6.z,r6.w,r7.x,r7.y,r7.z,r7.w};
        float4 w0=wp[2*c], w1=wp[2*c+1];
        float wv[5]={w0.x,w0.y,w0.z,w0.w,w1.x};
        #pragma unroll
        for(int j=0;j<32;j++){
          #pragma unroll
          for(int k=0;k<5;k++){
            int idx = j + k - 4;
            if(idx >= 0) acc[j] = fmaf(xr[idx], wv[k], acc[j]);
          }
        }
      }
      float s = epi2s[oc], bb = epi2b[oc];
      float m = 0.f;
      #pragma unroll
      for(int j=0;j<32;j++){ acc[j] = geluf(s*acc[j]+bb); m += acc[j]; }
      msh[oc] = m*(1.f/32.f);
      __syncthreads();
      if(tid < 16){
        float t2 = 0.f;
        for(int k=0;k<256;k++) t2 = fmaf(msh[k], se2w1[tid*256+k], t2);
        ysh[tid] = fmaxf(t2, 0.f);
      }
      __syncthreads();
      float t2 = 0.f;
      #pragma unroll
      for(int k=0;k<16;k++) t2 = fmaf(ysh[k], se2w2[oc*16+k], t2);
      float sc = sigmf(t2);
      #pragma unroll
      for(int j=0;j<32;j++) bufA[oc*32 + j] = acc[j]*sc;
      __syncthreads();
    }

    // ---- conv3: CIN=256, K=3, COUT=128 + BN + GELU + mean ----
    {
      float acc[16];
      #pragma unroll
      for(int j=0;j<16;j++) acc[j]=0.f;
      const float4* wp = (const float4*)(wc3p + (size_t)o*1024);
      if(lh == 0){
        for(int c=0;c<256;c++){
          const float4* rp = (const float4*)&bufA[c*32];
          float4 r0=rp[0], r1=rp[1], r2=rp[2], r3=rp[3];
          float xr[16]={r0.x,r0.y,r0.z,r0.w,r1.x,r1.y,r1.z,r1.w,
                        r2.x,r2.y,r2.z,r2.w,r3.x,r3.y,r3.z,r3.w};
          float4 w = wp[c];
          float wv[3]={w.x,w.y,w.z};
          #pragma unroll
          for(int j=0;j<16;j++){
            #pragma unroll
            for(int k=0;k<3;k++){
              int idx = j + k - 2;
              if(idx >= 0) acc[j] = fmaf(xr[idx], wv[k], acc[j]);
            }
          }
        }
      } else {
        for(int c=0;c<256;c++){
          const float4* rp = (const float4*)&bufA[c*32];
          float4 r3=rp[3], r4=rp[4], r5=rp[5], r6=rp[6], r7=rp[7];
          float xr[20]={r3.x,r3.y,r3.z,r3.w,r4.x,r4.y,r4.z,r4.w,
                        r5.x,r5.y,r5.z,r5.w,r6.x,r6.y,r6.z,r6.w,
                        r7.x,r7.y,r7.z,r7.w};                       // vals 12..31
          float4 w = wp[c];
          float wv[3]={w.x,w.y,w.z};
          #pragma unroll
          for(int j=0;j<16;j++){
            #pragma unroll
            for(int k=0;k<3;k++)
              acc[j] = fmaf(xr[j+k+2], wv[k], acc[j]);   // idx = 16+j-2+k = (j+k+2)+12
          }
        }
      }
      float s = epi3s[o], bb = epi3b[o];
      float m = 0.f;
      #pragma unroll
      for(int j=0;j<16;j++) m += geluf(s*acc[j]+bb);
      msh[lh*128 + o] = m;
      __syncthreads();
      if(tid < 128) x2f[cb*128 + tid] = (msh[tid] + msh[128+tid])*(1.f/32.f);
    }
  }
}

// ---------------- cluster pc: sim column sums, hn folded in (rawdot * rn_i * rn_t) ------
__global__ __launch_bounds__(256) void pc_kernel(const float* hseq, float* pcol, float* ccol)
{
  int blk = blockIdx.x; int b = blk>>3, chunk = blk&7;
  int tid = threadIdx.x; int il = tid & 31, ts = tid >> 5;
  int i = chunk*32 + il;
  const float4* hb = (const float4*)(hseq + (size_t)b*32768);
  __shared__ float rnsh[256];
  {
    const float4* rowp = hb + (size_t)tid*32;
    float ss = 0.f;
    #pragma unroll
    for(int r=0;r<32;r++){
      float4 v = rowp[r];
      ss = fmaf(v.x,v.x, fmaf(v.y,v.y, fmaf(v.z,v.z, fmaf(v.w,v.w, ss))));
    }
    rnsh[tid] = 1.f / fmaxf(sqrtf(ss), 1e-8f);
  }
  __syncthreads();
  float4 hi[32];
  #pragma unroll
  for(int r=0;r<32;r++) hi[r] = hb[(size_t)i*32 + r];
  float rni = rnsh[i];
  float ps=0.f, cs=0.f;
  for(int t=ts*32; t<ts*32+32; t++){
    float dx=0.f, dy=0.f, dz=0.f, dw=0.f;
    #pragma unroll
    for(int r=0;r<32;r++){
      float4 hv = hb[(size_t)t*32 + r];
      dx = fmaf(hi[r].x, hv.x, dx);
      dy = fmaf(hi[r].y, hv.y, dy);
      dz = fmaf(hi[r].z, hv.z, dz);
      dw = fmaf(hi[r].w, hv.w, dw);
    }
    float dot = ((dx+dy)+(dz+dw)) * rni * rnsh[t];
    float sim = (t==i) ? 0.f : expf(-5.5f*(1.0f - dot));
    cs += sim;
    if(t < i) ps += sim;
  }
  __shared__ float red[16][32];
  red[ts][il] = ps; red[8+ts][il] = cs;
  __syncthreads();
  if(tid < 32){
    float s=0.f;
    for(int r=0;r<8;r++) s += red[r][tid];
    pcol[b*256 + chunk*32 + tid] = s;
  } else if(tid < 64){
    int c2 = tid - 32; float s=0.f;
    for(int r=0;r<8;r++) s += red[8+r][c2];
    ccol[b*256 + chunk*32 + c2] = s;
  }
}

// ---------------- parallel prefix + dist + argmax + corr-features + last ----------------
__global__ __launch_bounds__(256) void cutcorr_kernel(
    const float* pcol, const float* ccol, const float* hseq,
    float* last, float* featA, int* cuts)
{
  int b = blockIdx.x, tid = threadIdx.x;
  __shared__ float D[256], RC[256], dist[256];
  __shared__ int cutsh;
  D[tid]  = 2.f*pcol[b*256+tid];
  RC[tid] = ccol[b*256+tid];
  __syncthreads();
  // Hillis-Steele inclusive scan (8 steps)
  #pragma unroll
  for(int off=1; off<256; off<<=1){
    float dv = (tid>=off) ? D[tid-off]  : 0.f;
    float rv = (tid>=off) ? RC[tid-off] : 0.f;
    __syncthreads();
    D[tid]  += dv;
    RC[tid] += rv;
    __syncthreads();
  }
  float tot = RC[255];
  if(tid < 255){
    float Dv = D[tid], Rv = RC[tid];
    float i_f = (float)(tid+1), j_f = 256.f - i_f;
    dist[tid] = Dv/(i_f*i_f) + (tot - 2.f*Rv + Dv)/(j_f*j_f) - 2.f*(Rv - Dv)/(i_f*j_f);
  }
  __syncthreads();
  if(tid == 0){
    float best = dist[0]; int bi = 0;
    for(int i=1;i<255;i++) if(dist[i] > best){ best = dist[i]; bi = i; }
    cutsh = bi + 1; cuts[b] = cutsh;
  }
  __syncthreads();
  int cut = cutsh;
  int k = tid & 127, half = tid >> 7;
  float s = 0.f;
  for(int t=half; t<cut; t+=2) s += hseq[((size_t)b*256+t)*128 + k];
  __shared__ float partial[2][128];
  partial[half][k] = s;
  __syncthreads();
  if(tid < 128){
    float cv = (partial[0][tid] + partial[1][tid]) / (float)cut;
    last[b*128+tid] = hseq[((size_t)b*256+255)*128 + tid];
    write_feat7(featA + ((size_t)(b*128+tid))*7, cv);
  }
}

// ---------------- KAN i-chunk partial, z-merged pair (mu/sd or mc/sc) ----------------
__global__ __launch_bounds__(256) void kanp2_kernel(
    const float* __restrict__ feat,
    const float* __restrict__ W1a, const float* __restrict__ B1a, const float* __restrict__ W2a,
    const float* __restrict__ W1b, const float* __restrict__ B1b, const float* __restrict__ W2b,
    int din, int dout, float* __restrict__ partial, int pstride)
{
  __shared__ float feat_s[32*225];
  __shared__ float red[8][32];
  int z = blockIdx.z;
  const float* W1 = z ? W1b : W1a;
  const float* B1 = z ? B1b : B1a;
  const float* W2 = z ? W2b : W2a;
  partial += (size_t)z * pstride;
  int j = blockIdx.x, ic = blockIdx.y;
  int i0 = ic*32;
  int tid = threadIdx.x;
  int b = tid & 31, hg = tid >> 5;
  for(int q=tid; q<1792; q+=256){
    int br = q/56, qq = q - br*56;
    float4 v = *(const float4*)(feat + ((size_t)br*din + i0)*7 + qq*4);
    float* d = &feat_s[br*225 + qq*4];
    d[0]=v.x; d[1]=v.y; d[2]=v.z; d[3]=v.w;
  }
  __syncthreads();
  float acc = 0.f;
  const float* fb = &feat_s[b*225];
  for(int ii=0; ii<32; ii++){
    int i = i0 + ii;
    size_t hbase = ((size_t)i*dout + j)*32 + hg*4;
    const float4* w1p = (const float4*)(W1 + ((size_t)i*dout + j)*224 + hg*28);
    float w1a[28];
    #pragma unroll
    for(int q=0;q<7;q++) *(float4*)&w1a[q*4] = w1p[q];
    float4 b1v = *(const float4*)(B1 + hbase);
    float4 w2v = *(const float4*)(W2 + hbase);
    float f[7];
    #pragma unroll
    for(int q=0;q<7;q++) f[q] = fb[ii*7+q];
    float b1a[4] = {b1v.x, b1v.y, b1v.z, b1v.w};
    float w2a[4] = {w2v.x, w2v.y, w2v.z, w2v.w};
    #pragma unroll
    for(int hh=0;hh<4;hh++){
      float hv = b1a[hh];
      #pragma unroll
      for(int q=0;q<7;q++) hv = fmaf(f[q], w1a[hh*7+q], hv);
      float sv = hv / (1.f + __expf(-hv));   // silu
      acc = fmaf(sv, w2a[hh], acc);
    }
  }
  red[hg][b] = acc;
  __syncthreads();
  if(tid < 32){
    float s = 0.f;
    #pragma unroll
    for(int q=0;q<8;q++) s += red[q][tid];
    partial[((size_t)ic*32 + tid)*dout + j] = s;
  }
}

// ---------------- fused kanr(mu)+kanr(sd)+zmix+featB ----------------
__global__ __launch_bounds__(256) void kanrz_kernel(
    const float* __restrict__ kp, const float* __restrict__ b2s,
    const float* __restrict__ eps1, const float* __restrict__ last, float* __restrict__ featB)
{
  int idx = blockIdx.x*256 + threadIdx.x;
  if(idx >= 4096) return;
  int b = idx >> 7, j = idx & 127;
  float mu = b2s[j], sd = b2s[128+j];
  #pragma unroll
  for(int ic=0; ic<4; ic++){
    mu += kp[((size_t)ic*32 + b)*128 + j];
    sd += kp[16384 + ((size_t)ic*32 + b)*128 + j];
  }
  float z = mu + softplusf(sd - 5.f)*eps1[idx];
  float lv = last[idx];
  write_feat7(featB + ((size_t)(b*256 + j))*7, lv);
  write_feat7(featB + ((size_t)(b*256 + 128 + j))*7, z);
}

// ---------------- fused kanr(mc)+kanr(sc)+xall+featC ----------------
__global__ __launch_bounds__(256) void kanrx_kernel(
    const float* __restrict__ kp, const float* __restrict__ b2s,
    const float* __restrict__ eps2, const float* __restrict__ x2f, float* __restrict__ featC)
{
  int idx = blockIdx.x*256 + threadIdx.x;
  if(idx >= 4096) return;
  int b = idx >> 7, j = idx & 127;
  float mu = b2s[256+j], sd = b2s[384+j];
  #pragma unroll
  for(int ic=0; ic<8; ic++){
    mu += kp[((size_t)ic*32 + b)*128 + j];
    sd += kp[32768 + ((size_t)ic*32 + b)*128 + j];
  }
  float v0 = mu + softplusf(sd - 5.f)*eps2[idx];
  float v1 = x2f[idx];
  write_feat7(featC + ((size_t)(b*256 + j))*7, v0);
  write_feat7(featC + ((size_t)(b*256 + 128 + j))*7, v1);
}

// ---------------- fc KAN single-pass: grid 10, ic-loop internal, writes d_out ----------
__global__ __launch_bounds__(256) void kanpfc_kernel(
    const float* __restrict__ feat, const float* __restrict__ W1,
    const float* __restrict__ B1, const float* __restrict__ W2,
    const float* __restrict__ b2s_fc, float* __restrict__ outp)
{
  __shared__ float feat_s[32*225];
  __shared__ float red[8][32];
  int j = blockIdx.x;
  int tid = threadIdx.x;
  int b = tid & 31, hg = tid >> 5;
  float acc = 0.f;
  for(int ic=0; ic<8; ic++){
    int i0 = ic*32;
    __syncthreads();
    for(int q=tid; q<1792; q+=256){
      int br = q/56, qq = q - br*56;
      float4 v = *(const float4*)(feat + ((size_t)br*256 + i0)*7 + qq*4);
      float* d = &feat_s[br*225 + qq*4];
      d[0]=v.x; d[1]=v.y; d[2]=v.z; d[3]=v.w;
    }
    __syncthreads();
    const float* fb = &feat_s[b*225];
    for(int ii=0; ii<32; ii++){
      int i = i0 + ii;
      size_t hbase = ((size_t)i*10 + j)*32 + hg*4;
      const float4* w1p = (const float4*)(W1 + ((size_t)i*10 + j)*224 + hg*28);
      float w1a[28];
      #pragma unroll
      for(int q=0;q<7;q++) *(float4*)&w1a[q*4] = w1p[q];
      float4 b1v = *(const float4*)(B1 + hbase);
      float4 w2v = *(const float4*)(W2 + hbase);
      float f[7];
      #pragma unroll
      for(int q=0;q<7;q++) f[q] = fb[ii*7+q];
      float b1a[4] = {b1v.x, b1v.y, b1v.z, b1v.w};
      float w2a[4] = {w2v.x, w2v.y, w2v.z, w2v.w};
      #pragma unroll
      for(int hh=0;hh<4;hh++){
        float hv = b1a[hh];
        #pragma unroll
        for(int q=0;q<7;q++) hv = fmaf(f[q], w1a[hh*7+q], hv);
        float sv = hv / (1.f + __expf(-hv));   // silu
        acc = fmaf(sv, w2a[hh], acc);
      }
    }
  }
  red[hg][b] = acc;
  __syncthreads();
  if(tid < 32){
    float s = b2s_fc[j];
    #pragma unroll
    for(int q=0;q<8;q++) s += red[q][tid];
    outp[tid*10 + j] = s;
  }
}

// ---------------- launch ----------------
extern "C" void kernel_launch(void* const* d_in, const int* in_sizes, int n_in,
                              void* d_out, int out_size, void* d_ws, size_t ws_size,
                              hipStream_t stream)
{
  const float* x    = (const float*)d_in[0];
  const float* we1  = (const float*)d_in[1];
  const float* be1  = (const float*)d_in[2];
  const float* e1g  = (const float*)d_in[3];
  const float* e1b  = (const float*)d_in[4];
  const float* e1m  = (const float*)d_in[5];
  const float* e1v  = (const float*)d_in[6];
  const float* we2  = (const float*)d_in[7];
  const float* be2  = (const float*)d_in[8];
  const float* e2g  = (const float*)d_in[9];
  const float* e2b  = (const float*)d_in[10];
  const float* e2m  = (const float*)d_in[11];
  const float* e2v  = (const float*)d_in[12];
  const float* wih  = (const float*)d_in[13];
  const float* whh  = (const float*)d_in[14];
  const float* bih  = (const float*)d_in[15];
  const float* bhh  = (const float*)d_in[16];
  const float* muW1 = (const float*)d_in[17];
  const float* muW2 = (const float*)d_in[18];
  const float* muB1 = (const float*)d_in[19];
  const float* muB2 = (const float*)d_in[20];
  const float* sdW1 = (const float*)d_in[21];
  const float* sdW2 = (const float*)d_in[22];
  const float* sdB1 = (const float*)d_in[23];
  const float* sdB2 = (const float*)d_in[24];
  const float* mcW1 = (const float*)d_in[25];
  const float* mcW2 = (const float*)d_in[26];
  const float* mcB1 = (const float*)d_in[27];
  const float* mcB2 = (const float*)d_in[28];
  const float* scW1 = (const float*)d_in[29];
  const float* scW2 = (const float*)d_in[30];
  const float* scB1 = (const float*)d_in[31];
  const float* scB2 = (const float*)d_in[32];
  const float* fcW1 = (const float*)d_in[33];
  const float* fcW2 = (const float*)d_in[34];
  const float* fcB1 = (const float*)d_in[35];
  const float* fcB2 = (const float*)d_in[36];
  const float* wc1  = (const float*)d_in[37];
  const float* bc1  = (const float*)d_in[38];
  const float* c1g  = (const float*)d_in[39];
  const float* c1b  = (const float*)d_in[40];
  const float* c1m  = (const float*)d_in[41];
  const float* c1v  = (const float*)d_in[42];
  const float* se1w1= (const float*)d_in[43];
  const float* se1w2= (const float*)d_in[44];
  const float* wc2  = (const float*)d_in[45];
  const float* bc2  = (const float*)d_in[46];
  const float* c2g  = (const float*)d_in[47];
  const float* c2b  = (const float*)d_in[48];
  const float* c2m  = (const float*)d_in[49];
  const float* c2v  = (const float*)d_in[50];
  const float* se2w1= (const float*)d_in[51];
  const float* se2w2= (const float*)d_in[52];
  const float* wc3  = (const float*)d_in[53];
  const float* bc3  = (const float*)d_in[54];
  const float* c3g  = (const float*)d_in[55];
  const float* c3b  = (const float*)d_in[56];
  const float* c3m  = (const float*)d_in[57];
  const float* c3v  = (const float*)d_in[58];
  const float* eps1 = (const float*)d_in[59];
  const float* eps2 = (const float*)d_in[60];

  float* ws = (float*)d_ws;
  float* kp   = ws + OFF_KP;   // mu/sd partials (16384 each)
  float* kp2  = ws + OFF_GX;   // mc/sc partials (32768 each) - GX dead after lstm
  float* b2s  = ws + OFF_B2S;

  prep_kernel<<<3984, 256, 0, stream>>>(we1, be1, e1g,e1b,e1m,e1v,
      we2, be2,e2g,e2b,e2m,e2v, wih,whh,bih,bhh,
      bc1,c1g,c1b,c1m,c1v, bc2,c2g,c2b,c2m,c2v, bc3,c3g,c3b,c3m,c3v,
      muB2, sdB2, mcB2, scB2, fcB2, wc2, wc3, ws);

  encoder_kernel<<<256, 256, 0, stream>>>(x, ws+OFF_W1F, ws+OFF_B1F,
      ws+OFF_S2E, ws+OFF_B2E, (const bf16*)(ws+OFF_WE2B), ws+OFF_XSRC);

  gates_kernel<<<256, 256, 0, stream>>>(ws+OFF_XSRC, ws+OFF_WIHT, ws+OFF_BIASG, ws+OFF_GX);

  // mega: lstm (blocks 0-31) + full conv/SE branch (blocks 32-63) overlapped
  lstm_conv_kernel<<<64, 256, 0, stream>>>(ws+OFF_GX, ws+OFF_WHHT, ws+OFF_HSEQ,
      x, wc1, ws+OFF_WC2P, ws+OFF_WC3P,
      ws+OFF_EPI1S, ws+OFF_EPI1B, ws+OFF_EPI2S, ws+OFF_EPI2B, ws+OFF_EPI3S, ws+OFF_EPI3B,
      se1w1, se1w2, se2w1, se2w2, ws+OFF_X2F);

  pc_kernel<<<256, 256, 0, stream>>>(ws+OFF_HSEQ, ws+OFF_PCOL, ws+OFF_CCOL);
  cutcorr_kernel<<<32, 256, 0, stream>>>(ws+OFF_PCOL, ws+OFF_CCOL, ws+OFF_HSEQ,
      ws+OFF_LAST, ws+OFF_FEATA, (int*)(ws+OFF_CUTS));

  kanp2_kernel<<<dim3(128,4,2), 256, 0, stream>>>(ws+OFF_FEATA,
      muW1, muB1, muW2, sdW1, sdB1, sdW2, 128, 128, kp, 16384);
  kanrz_kernel<<<16, 256, 0, stream>>>(kp, b2s, eps1, ws+OFF_LAST, ws+OFF_FEATB);

  kanp2_kernel<<<dim3(128,8,2), 256, 0, stream>>>(ws+OFF_FEATB,
      mcW1, mcB1, mcW2, scW1, scB1, scW2, 256, 128, kp2, 32768);
  kanrx_kernel<<<16, 256, 0, stream>>>(kp2, b2s, eps2, ws+OFF_X2F, ws+OFF_FEATC);

  kanpfc_kernel<<<10, 256, 0, stream>>>(ws+OFF_FEATC, fcW1, fcB1, fcW2,
      b2s+512, (float*)d_out);
}

// Round 11
// 845.964 us; speedup vs baseline: 1.2117x; 1.2117x over previous
//
#include <hip/hip_runtime.h>
#include <hip/hip_bf16.h>
#include <math.h>

typedef __hip_bfloat16 bf16;

#define DEV static __device__ __forceinline__

DEV float geluf(float x){ return 0.5f*x*(1.0f + erff(x*0.70710678118654752f)); }
DEV float sigmf(float x){ return 1.0f/(1.0f + __expf(-x)); }
DEV float softplusf(float x){ return (x > 15.f) ? x : log1pf(__expf(x)); }
DEV float tanhfast(float x){ float e = __expf(2.f*x); return fmaf(-2.f, 1.f/(e+1.f), 1.f); }

typedef __attribute__((ext_vector_type(8))) short v8s;   // 8 bf16 (4 VGPRs)
typedef __attribute__((ext_vector_type(4))) float v4f;   // 4 fp32 acc
typedef _Float16 f16;
typedef f16 h2 __attribute__((ext_vector_type(2)));
typedef f16 f16x8 __attribute__((ext_vector_type(8)));   // 16B chunk (4 h2)
typedef unsigned u32x4 __attribute__((ext_vector_type(4)));

DEV float dot2f(h2 a, h2 b, float c){
#if __has_builtin(__builtin_amdgcn_fdot2)
  return __builtin_amdgcn_fdot2(a, b, c, false);
#else
  return fmaf((float)a.y, (float)b.y, fmaf((float)a.x, (float)b.x, c));
#endif
}

DEV h2 geth2(f16x8 v, int j){ h2 r; r.x = v[2*j]; r.y = v[2*j+1]; return r; }

// LDS-only barrier (lstm path): orders ds ops, leaves global loads in flight.
DEV void lds_barrier(){
  asm volatile("s_waitcnt lgkmcnt(0)" ::: "memory");
  __builtin_amdgcn_s_barrier();
  __builtin_amdgcn_sched_barrier(0);
}

DEV void write_feat7(float* fp, float v){
  fp[0]=v;
  fp[1]=sinf(v); fp[2]=sinf(2.f*v); fp[3]=sinf(4.f*v);
  fp[4]=cosf(v); fp[5]=cosf(2.f*v); fp[6]=cosf(4.f*v);
}

// ---------------- workspace layout (float offsets) ----------------
enum : size_t {
  OFF_W1F   = 0,        // 2048  folded enc conv1 weights (256x8)
  OFF_B1F   = 2048,     // 256
  OFF_S2E   = 2304,     // 64
  OFF_B2E   = 2368,     // 64
  OFF_WIHT  = 2432,     // 32768 w_ih^T (64x512)
  OFF_BIASG = 35200,    // 512   b_ih+b_hh
  OFF_WHHT  = 35712,    // whh packed f16 pairs, GATE-major: h2[512][64]
  OFF_EPI1S = 101248,   // 128
  OFF_EPI1B = 101376,   // 128
  OFF_EPI2S = 101504,   // 256
  OFF_EPI2B = 101760,   // 256
  OFF_EPI3S = 102016,   // 128
  OFF_EPI3B = 102144,   // 128
  OFF_WE2B  = 102272,   // 262144 floats = 524288 bf16: we2 repacked [o][e][f]
  OFF_XSRC  = 364416,   // 524288 (B,T,64)
  OFF_GX    = 888704,   // 4194304 (B,T,512); reused as kanp(mc/sc) partials after lstm
  OFF_HSEQ  = 5083008,  // 1048576 (B,T,128)
  OFF_PCOL  = 7180160,  // 8192
  OFF_CCOL  = 7188352,  // 8192
  OFF_CUTS  = 7196544,  // 32 (int)
  OFF_LAST  = 7196576,  // 4096
  OFF_FEATA = 7204768,  // 28672 (B,128,7)
  OFF_FEATB = 7249824,  // 57344 (B,256,7)
  OFF_WC3P  = 7315360,  // 131072 wc3 padded [128][256][4]
  OFF_WC2P  = 7446432,  // 262144 wc2 padded [256][128][8]
  OFF_KP    = 7708576,  // 32768 kan partials: mu at +0, sd at +16384; fc reuses +0
  OFF_B2S   = 7741344,  // 522: per-kan sum_i B2: mu+0,std+128,muc+256,stdc+384,fc+512
  OFF_X2F   = 7839648,  // 4096
  OFF_FEATC = 7851936,  // 57344
  WS_FLOATS = 7909280
};

// ---------------- prep: fold BN, pack LSTM weights, repack we2, pad wc2/wc3, B2 sums ----
__global__ __launch_bounds__(256) void prep_kernel(
    const float* we1, const float* be1,
    const float* e1g, const float* e1b, const float* e1m, const float* e1v,
    const float* we2, const float* be2, const float* e2g, const float* e2b, const float* e2m, const float* e2v,
    const float* wih, const float* whh, const float* bih, const float* bhh,
    const float* bc1, const float* c1g, const float* c1b, const float* c1m, const float* c1v,
    const float* bc2, const float* c2g, const float* c2b, const float* c2m, const float* c2v,
    const float* bc3, const float* c3g, const float* c3b, const float* c3m, const float* c3v,
    const float* muB2, const float* sdB2, const float* mcB2, const float* scB2, const float* fcB2,
    const float* wc2, const float* wc3,
    float* ws)
{
  int idx = blockIdx.x*256 + threadIdx.x;
  if(idx < 2048){
    int o = idx>>3;
    float s = e1g[o] * rsqrtf(e1v[o] + 1e-5f);
    ws[OFF_W1F + idx] = we1[idx] * s;
  } else if(idx < 2304){
    int o = idx - 2048;
    float s = e1g[o] * rsqrtf(e1v[o] + 1e-5f);
    ws[OFF_B1F + o] = s*(be1[o] - e1m[o]) + e1b[o];
  } else if(idx < 2368){
    int e = idx - 2304;
    float s = e2g[e] * rsqrtf(e2v[e] + 1e-5f);
    ws[OFF_S2E + e] = s;
    ws[OFF_B2E + e] = s*(be2[e] - e2m[e]) + e2b[e];
  } else if(idx < 35136){
    int q = idx - 2368; int e = q>>9, g = q&511;
    ws[OFF_WIHT + q] = wih[g*64 + e];
  } else if(idx < 35648){
    int g = idx - 35136;
    ws[OFF_BIASG + g] = bih[g] + bhh[g];
  } else if(idx < 101184){
    int q = idx - 35648;
    if(q < 32768){
      int k2 = q>>9, g = q&511;
      h2 v;
      v.x = (f16)whh[g*128 + 2*k2];
      v.y = (f16)whh[g*128 + 2*k2 + 1];
      ((h2*)(ws + OFF_WHHT))[g*64 + k2] = v;
    }
  } else if(idx < 101312){
    int o = idx - 101184;
    float s = c1g[o] * rsqrtf(c1v[o] + 1e-3f);
    ws[OFF_EPI1S + o] = s;
    ws[OFF_EPI1B + o] = s*(bc1[o] - c1m[o]) + c1b[o];
  } else if(idx < 101568){
    int o = idx - 101312;
    float s = c2g[o] * rsqrtf(c2v[o] + 1e-3f);
    ws[OFF_EPI2S + o] = s;
    ws[OFF_EPI2B + o] = s*(bc2[o] - c2m[o]) + c2b[o];
  } else if(idx < 101696){
    int o = idx - 101568;
    float s = c3g[o] * rsqrtf(c3v[o] + 1e-3f);
    ws[OFF_EPI3S + o] = s;
    ws[OFF_EPI3B + o] = s*(bc3[o] - c3m[o]) + c3b[o];
  } else if(idx < 625984){
    int q = idx - 101696;
    int o = q >> 11, rem = q & 2047;
    int e = rem >> 5, f = rem & 31;
    bf16* Wr = (bf16*)(ws + OFF_WE2B);
    Wr[q] = __float2bfloat16(we2[(size_t)e*8192 + o*32 + f]);
  } else if(idx < 626112){
    int j = idx - 625984; float s = 0.f;
    for(int i=0;i<128;i++) s += muB2[i*128+j];
    ws[OFF_B2S + j] = s;
  } else if(idx < 626240){
    int j = idx - 626112; float s = 0.f;
    for(int i=0;i<128;i++) s += sdB2[i*128+j];
    ws[OFF_B2S + 128 + j] = s;
  } else if(idx < 626368){
    int j = idx - 626240; float s = 0.f;
    for(int i=0;i<256;i++) s += mcB2[i*128+j];
    ws[OFF_B2S + 256 + j] = s;
  } else if(idx < 626496){
    int j = idx - 626368; float s = 0.f;
    for(int i=0;i<256;i++) s += scB2[i*128+j];
    ws[OFF_B2S + 384 + j] = s;
  } else if(idx < 626506){
    int j = idx - 626496; float s = 0.f;
    for(int i=0;i<256;i++) s += fcB2[i*10+j];
    ws[OFF_B2S + 512 + j] = s;
  } else if(idx < 888650){
    // wc2 pad: [256][128][5] -> [256][128][8] (float4-loadable)
    int q = idx - 626506;
    int o = q >> 10, rem = q & 1023;
    int c = rem >> 3, k = rem & 7;
    ws[OFF_WC2P + q] = (k < 5) ? wc2[(size_t)o*640 + c*5 + k] : 0.f;
  } else if(idx < 1019722){
    // wc3 pad: [128][256][3] -> [128][256][4]
    int q = idx - 888650;
    int o = q >> 10, rem = q & 1023;
    int c = rem >> 2, k = rem & 3;
    ws[OFF_WC3P + q] = (k < 3) ? wc3[(size_t)o*768 + c*3 + k] : 0.f;
  }
}

// ---------------- encoder: conv1(1x8 SAME)+BN+GELU fused into bf16 MFMA GEMM ----------------
__global__ __launch_bounds__(256,1) void encoder_kernel(
    const float* __restrict__ x, const float* __restrict__ w1f, const float* __restrict__ b1f,
    const float* __restrict__ s2e, const float* __restrict__ b2e,
    const bf16* __restrict__ Wr, float* __restrict__ x_src)
{
  __shared__ float xs[39*32];
  __shared__ float w1s[2048];
  __shared__ float b1s[256];
  __shared__ __align__(16) unsigned short At[2][32*136];
  __shared__ __align__(16) unsigned short Bt[2][4*2560];

  int blk = blockIdx.x; int b = blk>>3; int t0 = (blk&7)*32;
  int tid = threadIdx.x;

  for(int i=tid;i<2048;i+=256) w1s[i] = w1f[i];
  b1s[tid] = b1f[tid];
  for(int i=tid;i<39*32;i+=256){
    int r=i>>5, f=i&31; int t=t0-3+r;
    xs[i] = (t>=0 && t<256) ? x[(b*256+t)*32+f] : 0.f;
  }
  __syncthreads();

  int f = tid & 31, tq = tid >> 5;
  int lane = tid & 63, w = tid >> 6;
  int wm = w & 1, wn = w >> 1;
  int m0 = wm*16, n0 = wn*32;
  int l15 = lane & 15, quad = lane >> 4;

  const v8s* Wv = (const v8s*)Wr;

  auto stage = [&](int cc, int buf){
    v8s bw[4];
    #pragma unroll
    for(int i=0;i<4;i++) bw[i] = Wv[cc*1024 + i*256 + tid];
    unsigned short aval[16];
    #pragma unroll
    for(int ol=0;ol<4;ol++){
      int o = cc*4 + ol;
      float wv[8];
      #pragma unroll
      for(int j=0;j<8;j++) wv[j] = w1s[o*8+j];
      float bb = b1s[o];
      #pragma unroll
      for(int i=0;i<4;i++){
        int tl = tq*4 + i;
        float c = bb;
        #pragma unroll
        for(int j=0;j<8;j++) c = fmaf(wv[j], xs[(tl+j)*32+f], c);
        aval[ol*4+i] = ((__hip_bfloat16_raw)__float2bfloat16(geluf(c))).x;
      }
    }
    #pragma unroll
    for(int ol=0;ol<4;ol++){
      #pragma unroll
      for(int i=0;i<4;i++)
        At[buf][(tq*4+i)*136 + ol*32 + f] = aval[ol*4+i];
    }
    #pragma unroll
    for(int i=0;i<4;i++){
      int j = i*256 + tid;
      int ol = j>>8, e = (j&255)>>2, f8 = j&3;
      *(v8s*)&Bt[buf][ol*2560 + e*40 + f8*8] = bw[i];
    }
  };

  stage(0, 0);
  __syncthreads();

  v4f acc0 = {0.f,0.f,0.f,0.f}, acc1 = {0.f,0.f,0.f,0.f};

  for(int c=0;c<64;c++){
    int p = c & 1, q = p ^ 1;
    if(c < 63) stage(c+1, q);
    #pragma unroll
    for(int ol=0;ol<4;ol++){
      v8s av = *(const v8s*)&At[p][(m0+l15)*136 + ol*32 + quad*8];
      v8s b0 = *(const v8s*)&Bt[p][ol*2560 + (n0+l15)*40 + quad*8];
      v8s b1 = *(const v8s*)&Bt[p][ol*2560 + (n0+16+l15)*40 + quad*8];
      acc0 = __builtin_amdgcn_mfma_f32_16x16x32_bf16(av, b0, acc0, 0, 0, 0);
      acc1 = __builtin_amdgcn_mfma_f32_16x16x32_bf16(av, b1, acc1, 0, 0, 0);
    }
    __syncthreads();
  }

  #pragma unroll
  for(int r=0;r<4;r++){
    int t = t0 + m0 + quad*4 + r;
    int e0 = n0 + l15;
    float v0 = geluf(s2e[e0]*acc0[r] + b2e[e0]);
    x_src[((size_t)(b*256+t))*64 + e0] = v0;
    int e1 = e0 + 16;
    float v1 = geluf(s2e[e1]*acc1[r] + b2e[e1]);
    x_src[((size_t)(b*256+t))*64 + e1] = v1;
  }
}

// ---------------- gates_x = x_src @ w_ih^T + bias ----------------
__global__ __launch_bounds__(256) void gates_kernel(
    const float* x_src, const float* wihT, const float* biasg, float* gx)
{
  __shared__ float xsh[32*64];
  int blk = blockIdx.x; int b = blk>>3, t0 = (blk&7)*32;
  int tid = threadIdx.x;
  for(int i=tid;i<2048;i+=256) xsh[i] = x_src[((size_t)b*256+t0)*64 + i];
  __syncthreads();
  int g0 = tid, g1 = tid + 256;
  float acc0[32], acc1[32];
  #pragma unroll
  for(int tt=0;tt<32;tt++){ acc0[tt]=0.f; acc1[tt]=0.f; }
  for(int e=0;e<64;e++){
    float w0 = wihT[e*512+g0], w1 = wihT[e*512+g1];
    #pragma unroll
    for(int tt=0;tt<32;tt++){
      float xv = xsh[tt*64+e];
      acc0[tt] = fmaf(xv, w0, acc0[tt]);
      acc1[tt] = fmaf(xv, w1, acc1[tt]);
    }
  }
  float bg0 = biasg[g0], bg1 = biasg[g1];
  #pragma unroll
  for(int tt=0;tt<32;tt++){
    gx[((size_t)b*256+t0+tt)*512 + g0] = acc0[tt] + bg0;
    gx[((size_t)b*256+t0+tt)*512 + g1] = acc1[tt] + bg1;
  }
}

// ---------------- MEGA kernel: blocks 0-31 = LSTM; 32-63 = conv/SE branch (hidden) -----
#define LSTM_STEP(GI, GF, GG, GO, PR, PW, T)                                 \
  {                                                                          \
    const f16x8* hp = (const f16x8*)&hsh[PR][half*64];                       \
    f16x8 hvv[8];                                                            \
    _Pragma("unroll")                                                        \
    for(int q=0;q<8;q++) hvv[q] = hp[q];                                     \
    float si=0.f, sf=0.f, sg=0.f, so=0.f;                                    \
    _Pragma("unroll")                                                        \
    for(int q=0;q<8;q++){                                                    \
      f16x8 Wi = __builtin_bit_cast(f16x8, wi[q]);                           \
      f16x8 Wf = __builtin_bit_cast(f16x8, wf[q]);                           \
      f16x8 Wg = __builtin_bit_cast(f16x8, wg[q]);                           \
      f16x8 Wo = __builtin_bit_cast(f16x8, wo[q]);                           \
      f16x8 hq = hvv[q];                                                     \
      _Pragma("unroll")                                                      \
      for(int j=0;j<4;j++){                                                  \
        h2 hj = geth2(hq, j);                                                \
        si = dot2f(hj, geth2(Wi,j), si);                                     \
        sf = dot2f(hj, geth2(Wf,j), sf);                                     \
        sg = dot2f(hj, geth2(Wg,j), sg);                                     \
        so = dot2f(hj, geth2(Wo,j), so);                                     \
      }                                                                      \
    }                                                                        \
    si += __shfl_xor(si, 32, 64);                                            \
    sf += __shfl_xor(sf, 32, 64);                                            \
    sg += __shfl_xor(sg, 32, 64);                                            \
    so += __shfl_xor(so, 32, 64);                                            \
    float iv = sigmf(si + (GI));                                             \
    float fv = sigmf(sf + (GF));                                             \
    float gv = tanhfast(sg + (GG));                                          \
    float ov = sigmf(so + (GO));                                             \
    c = fmaf(fv, c, iv*gv);                                                  \
    float h = ov*tanhfast(c);                                                \
    if(half == 0){                                                           \
      hsh[PW][n] = (f16)h;                                                   \
      hseq[((size_t)b*256+(T))*128 + n] = h;                                 \
    }                                                                        \
    lds_barrier();                                                           \
  }

__global__ __launch_bounds__(256)
__attribute__((amdgpu_waves_per_eu(1,1)))
void lstm_conv_kernel(
    const float* __restrict__ gates_x, const float* __restrict__ whh16f, float* __restrict__ hseq,
    const float* __restrict__ x,
    const float* __restrict__ wc1, const float* __restrict__ wc2p, const float* __restrict__ wc3p,
    const float* __restrict__ epi1s, const float* __restrict__ epi1b,
    const float* __restrict__ epi2s, const float* __restrict__ epi2b,
    const float* __restrict__ epi3s, const float* __restrict__ epi3b,
    const float* __restrict__ se1w1, const float* __restrict__ se1w2,
    const float* __restrict__ se2w1, const float* __restrict__ se2w2,
    float* __restrict__ x2f)
{
  __shared__ __align__(16) f16 hsh[2][128];
  __shared__ __align__(16) float bufA[8192];   // conv: x (256x32), later y2 (256x32)
  __shared__ __align__(16) float bufB[4096];   // conv: y1 (128x32)
  __shared__ float msh[256];
  __shared__ float ysh[16];

  int tid = threadIdx.x;
  if(blockIdx.x < 32){
    // ---------------- LSTM path (R7 structure, 177us floor) ----------------
    int b = blockIdx.x;
    int wave = tid >> 6, lane = tid & 63;
    int half = lane >> 5;
    int n = wave*32 + (lane & 31);

    const u32x4* Wp = (const u32x4*)whh16f;
    u32x4 wi[8], wf[8], wg[8], wo[8];
    #pragma unroll
    for(int q=0;q<8;q++){
      wi[q] = Wp[(size_t)(n      )*16 + half*8 + q];
      wf[q] = Wp[(size_t)(n + 128)*16 + half*8 + q];
      wg[q] = Wp[(size_t)(n + 256)*16 + half*8 + q];
      wo[q] = Wp[(size_t)(n + 384)*16 + half*8 + q];
    }
    asm volatile("" :
      "+v"(wi[0]), "+v"(wi[1]), "+v"(wi[2]), "+v"(wi[3]),
      "+v"(wi[4]), "+v"(wi[5]), "+v"(wi[6]), "+v"(wi[7]),
      "+v"(wf[0]), "+v"(wf[1]), "+v"(wf[2]), "+v"(wf[3]),
      "+v"(wf[4]), "+v"(wf[5]), "+v"(wf[6]), "+v"(wf[7]));
    asm volatile("" :
      "+v"(wg[0]), "+v"(wg[1]), "+v"(wg[2]), "+v"(wg[3]),
      "+v"(wg[4]), "+v"(wg[5]), "+v"(wg[6]), "+v"(wg[7]),
      "+v"(wo[0]), "+v"(wo[1]), "+v"(wo[2]), "+v"(wo[3]),
      "+v"(wo[4]), "+v"(wo[5]), "+v"(wo[6]), "+v"(wo[7]));

    if(tid < 128) hsh[0][tid] = (f16)0.f;
    float c = 0.f;
    const float* gx = gates_x + (size_t)b*256*512;
    float i0v = gx[n], f0v = gx[128+n], g0v = gx[256+n], o0v = gx[384+n];
    float i1v = gx[512+n], f1v = gx[512+128+n], g1v = gx[512+256+n], o1v = gx[512+384+n];
    __syncthreads();
    for(int t=0; t<256; t+=2){
      float i2v=0.f,f2v=0.f,g2v=0.f,o2v=0.f,i3v=0.f,f3v=0.f,g3v=0.f,o3v=0.f;
      if(t+2 < 256){
        const float* gp = gx + (size_t)(t+2)*512;
        i2v = gp[n]; f2v = gp[128+n]; g2v = gp[256+n]; o2v = gp[384+n];
      }
      LSTM_STEP(i0v, f0v, g0v, o0v, 0, 1, t);
      if(t+3 < 256){
        const float* gp = gx + (size_t)(t+3)*512;
        i3v = gp[n]; f3v = gp[128+n]; g3v = gp[256+n]; o3v = gp[384+n];
      }
      LSTM_STEP(i1v, f1v, g1v, o1v, 1, 0, t+1);
      i0v=i2v; f0v=f2v; g0v=g2v; o0v=o2v;
      i1v=i3v; f1v=f3v; g1v=g3v; o1v=o3v;
    }
  } else {
    // ---------------- conv branch: one block per batch ----------------
    int cb = blockIdx.x - 32;
    for(int i=tid; i<8192; i+=256) bufA[i] = x[(size_t)cb*8192 + i];
    __syncthreads();

    int wv_ = tid >> 6, ln = tid & 63;
    int lh = wv_ >> 1;                 // waves 0,1: lower 16 l; waves 2,3: upper
    int o  = ((wv_ & 1) << 6) | ln;    // 0..127

    // ---- conv1: CIN=256, K=8, COUT=128; (o, lh) per thread, L=16 ----
    {
      float acc[16];
      #pragma unroll
      for(int j=0;j<16;j++) acc[j]=0.f;
      const float4* wp = (const float4*)(wc1 + (size_t)o*2048);
      if(lh == 0){
        for(int c=0;c<256;c++){
          const float4* rp = (const float4*)&bufA[c*32];
          float4 r0=rp[0], r1=rp[1], r2=rp[2], r3=rp[3];
          float xr[16]={r0.x,r0.y,r0.z,r0.w,r1.x,r1.y,r1.z,r1.w,
                        r2.x,r2.y,r2.z,r2.w,r3.x,r3.y,r3.z,r3.w};
          float4 w0=wp[2*c], w1=wp[2*c+1];
          float wv[8]={w0.x,w0.y,w0.z,w0.w,w1.x,w1.y,w1.z,w1.w};
          #pragma unroll
          for(int j=0;j<16;j++){
            #pragma unroll
            for(int k=0;k<8;k++){
              int idx = j + k - 7;
              if(idx >= 0) acc[j] = fmaf(xr[idx], wv[k], acc[j]);
            }
          }
        }
      } else {
        for(int c=0;c<256;c++){
          const float4* rp = (const float4*)&bufA[c*32];
          float4 r2=rp[2], r3=rp[3], r4=rp[4], r5=rp[5], r6=rp[6], r7=rp[7];
          float xr[24]={r2.x,r2.y,r2.z,r2.w,r3.x,r3.y,r3.z,r3.w,
                        r4.x,r4.y,r4.z,r4.w,r5.x,r5.y,r5.z,r5.w,
                        r6.x,r6.y,r6.z,r6.w,r7.x,r7.y,r7.z,r7.w};  // vals 8..31
          float4 w0=wp[2*c], w1=wp[2*c+1];
          float wv[8]={w0.x,w0.y,w0.z,w0.w,w1.x,w1.y,w1.z,w1.w};
          #pragma unroll
          for(int j=0;j<16;j++){
            #pragma unroll
            for(int k=0;k<8;k++)
              acc[j] = fmaf(xr[j+k+1], wv[k], acc[j]);   // idx = 16+j-7+k = (j+k+1)+8
          }
        }
      }
      float s = epi1s[o], bb = epi1b[o];
      float g[16]; float m = 0.f;
      #pragma unroll
      for(int j=0;j<16;j++){ g[j] = geluf(s*acc[j]+bb); m += g[j]; }
      msh[lh*128 + o] = m;
      __syncthreads();
      if(tid < 8){
        float t2 = 0.f;
        for(int k=0;k<128;k++) t2 = fmaf((msh[k]+msh[128+k])*(1.f/32.f), se1w1[tid*128+k], t2);
        ysh[tid] = fmaxf(t2, 0.f);
      }
      __syncthreads();
      float t2 = 0.f;
      #pragma unroll
      for(int k=0;k<8;k++) t2 = fmaf(ysh[k], se1w2[o*8+k], t2);
      float sc = sigmf(t2);
      #pragma unroll
      for(int j=0;j<16;j++) bufB[o*32 + lh*16 + j] = g[j]*sc;
      __syncthreads();
    }

    // ---- conv2: CIN=128, K=5, COUT=256; o = tid, L=32 ----
    {
      int oc = tid;
      float acc[32];
      #pragma unroll
      for(int j=0;j<32;j++) acc[j]=0.f;
      const float4* wp = (const float4*)(wc2p + (size_t)oc*1024);
      for(int c=0;c<128;c++){
        const float4* rp = (const float4*)&bufB[c*32];
        float4 r0=rp[0],r1=rp[1],r2=rp[2],r3=rp[3],r4=rp[4],r5=rp[5],r6=rp[6],r7=rp[7];
        float xr[32]={r0.x,r0.y,r0.z,r0.w,r1.x,r1.y,r1.z,r1.w,
                      r2.x,r2.y,r2.z,r2.w,r3.x,r3.y,r3.z,r3.w,
                      r4.x,r4.y,r4.z,r4.w,r5.x,r5.y,r5.z,r5.w,
                      r6.x,r6.y,r6.z,r6.w,r7.x,r7.y,r7.z,r7.w};
        float4 w0=wp[2*c], w1=wp[2*c+1];
        float wv[5]={w0.x,w0.y,w0.z,w0.w,w1.x};
        #pragma unroll
        for(int j=0;j<32;j++){
          #pragma unroll
          for(int k=0;k<5;k++){
            int idx = j + k - 4;
            if(idx >= 0) acc[j] = fmaf(xr[idx], wv[k], acc[j]);
          }
        }
      }
      float s = epi2s[oc], bb = epi2b[oc];
      float m = 0.f;
      #pragma unroll
      for(int j=0;j<32;j++){ acc[j] = geluf(s*acc[j]+bb); m += acc[j]; }
      msh[oc] = m*(1.f/32.f);
      __syncthreads();
      if(tid < 16){
        float t2 = 0.f;
        for(int k=0;k<256;k++) t2 = fmaf(msh[k], se2w1[tid*256+k], t2);
        ysh[tid] = fmaxf(t2, 0.f);
      }
      __syncthreads();
      float t2 = 0.f;
      #pragma unroll
      for(int k=0;k<16;k++) t2 = fmaf(ysh[k], se2w2[oc*16+k], t2);
      float sc = sigmf(t2);
      #pragma unroll
      for(int j=0;j<32;j++) bufA[oc*32 + j] = acc[j]*sc;
      __syncthreads();
    }

    // ---- conv3: CIN=256, K=3, COUT=128 + BN + GELU + mean ----
    {
      float acc[16];
      #pragma unroll
      for(int j=0;j<16;j++) acc[j]=0.f;
      const float4* wp = (const float4*)(wc3p + (size_t)o*1024);
      if(lh == 0){
        for(int c=0;c<256;c++){
          const float4* rp = (const float4*)&bufA[c*32];
          float4 r0=rp[0], r1=rp[1], r2=rp[2], r3=rp[3];
          float xr[16]={r0.x,r0.y,r0.z,r0.w,r1.x,r1.y,r1.z,r1.w,
                        r2.x,r2.y,r2.z,r2.w,r3.x,r3.y,r3.z,r3.w};
          float4 w = wp[c];
          float wv[3]={w.x,w.y,w.z};
          #pragma unroll
          for(int j=0;j<16;j++){
            #pragma unroll
            for(int k=0;k<3;k++){
              int idx = j + k - 2;
              if(idx >= 0) acc[j] = fmaf(xr[idx], wv[k], acc[j]);
            }
          }
        }
      } else {
        for(int c=0;c<256;c++){
          const float4* rp = (const float4*)&bufA[c*32];
          float4 r3=rp[3], r4=rp[4], r5=rp[5], r6=rp[6], r7=rp[7];
          float xr[20]={r3.x,r3.y,r3.z,r3.w,r4.x,r4.y,r4.z,r4.w,
                        r5.x,r5.y,r5.z,r5.w,r6.x,r6.y,r6.z,r6.w,
                        r7.x,r7.y,r7.z,r7.w};                       // vals 12..31
          float4 w = wp[c];
          float wv[3]={w.x,w.y,w.z};
          #pragma unroll
          for(int j=0;j<16;j++){
            #pragma unroll
            for(int k=0;k<3;k++)
              acc[j] = fmaf(xr[j+k+2], wv[k], acc[j]);   // idx = 16+j-2+k = (j+k+2)+12
          }
        }
      }
      float s = epi3s[o], bb = epi3b[o];
      float m = 0.f;
      #pragma unroll
      for(int j=0;j<16;j++) m += geluf(s*acc[j]+bb);
      msh[lh*128 + o] = m;
      __syncthreads();
      if(tid < 128) x2f[cb*128 + tid] = (msh[tid] + msh[128+tid])*(1.f/32.f);
    }
  }
}

// ---------------- cluster pc: sim column sums, hn folded in (rawdot * rn_i * rn_t) ------
__global__ __launch_bounds__(256) void pc_kernel(const float* hseq, float* pcol, float* ccol)
{
  int blk = blockIdx.x; int b = blk>>3, chunk = blk&7;
  int tid = threadIdx.x; int il = tid & 31, ts = tid >> 5;
  int i = chunk*32 + il;
  const float4* hb = (const float4*)(hseq + (size_t)b*32768);
  __shared__ float rnsh[256];
  {
    const float4* rowp = hb + (size_t)tid*32;
    float ss = 0.f;
    #pragma unroll
    for(int r=0;r<32;r++){
      float4 v = rowp[r];
      ss = fmaf(v.x,v.x, fmaf(v.y,v.y, fmaf(v.z,v.z, fmaf(v.w,v.w, ss))));
    }
    rnsh[tid] = 1.f / fmaxf(sqrtf(ss), 1e-8f);
  }
  __syncthreads();
  float4 hi[32];
  #pragma unroll
  for(int r=0;r<32;r++) hi[r] = hb[(size_t)i*32 + r];
  float rni = rnsh[i];
  float ps=0.f, cs=0.f;
  for(int t=ts*32; t<ts*32+32; t++){
    float dx=0.f, dy=0.f, dz=0.f, dw=0.f;
    #pragma unroll
    for(int r=0;r<32;r++){
      float4 hv = hb[(size_t)t*32 + r];
      dx = fmaf(hi[r].x, hv.x, dx);
      dy = fmaf(hi[r].y, hv.y, dy);
      dz = fmaf(hi[r].z, hv.z, dz);
      dw = fmaf(hi[r].w, hv.w, dw);
    }
    float dot = ((dx+dy)+(dz+dw)) * rni * rnsh[t];
    float sim = (t==i) ? 0.f : expf(-5.5f*(1.0f - dot));
    cs += sim;
    if(t < i) ps += sim;
  }
  __shared__ float red[16][32];
  red[ts][il] = ps; red[8+ts][il] = cs;
  __syncthreads();
  if(tid < 32){
    float s=0.f;
    for(int r=0;r<8;r++) s += red[r][tid];
    pcol[b*256 + chunk*32 + tid] = s;
  } else if(tid < 64){
    int c2 = tid - 32; float s=0.f;
    for(int r=0;r<8;r++) s += red[8+r][c2];
    ccol[b*256 + chunk*32 + c2] = s;
  }
}

// ---------------- parallel prefix + dist + argmax + corr-features + last ----------------
__global__ __launch_bounds__(256) void cutcorr_kernel(
    const float* pcol, const float* ccol, const float* hseq,
    float* last, float* featA, int* cuts)
{
  int b = blockIdx.x, tid = threadIdx.x;
  __shared__ float D[256], RC[256], dist[256];
  __shared__ int cutsh;
  D[tid]  = 2.f*pcol[b*256+tid];
  RC[tid] = ccol[b*256+tid];
  __syncthreads();
  // Hillis-Steele inclusive scan (8 steps)
  #pragma unroll
  for(int off=1; off<256; off<<=1){
    float dv = (tid>=off) ? D[tid-off]  : 0.f;
    float rv = (tid>=off) ? RC[tid-off] : 0.f;
    __syncthreads();
    D[tid]  += dv;
    RC[tid] += rv;
    __syncthreads();
  }
  float tot = RC[255];
  if(tid < 255){
    float Dv = D[tid], Rv = RC[tid];
    float i_f = (float)(tid+1), j_f = 256.f - i_f;
    dist[tid] = Dv/(i_f*i_f) + (tot - 2.f*Rv + Dv)/(j_f*j_f) - 2.f*(Rv - Dv)/(i_f*j_f);
  }
  __syncthreads();
  if(tid == 0){
    float best = dist[0]; int bi = 0;
    for(int i=1;i<255;i++) if(dist[i] > best){ best = dist[i]; bi = i; }
    cutsh = bi + 1; cuts[b] = cutsh;
  }
  __syncthreads();
  int cut = cutsh;
  int k = tid & 127, half = tid >> 7;
  float s = 0.f;
  for(int t=half; t<cut; t+=2) s += hseq[((size_t)b*256+t)*128 + k];
  __shared__ float partial[2][128];
  partial[half][k] = s;
  __syncthreads();
  if(tid < 128){
    float cv = (partial[0][tid] + partial[1][tid]) / (float)cut;
    last[b*128+tid] = hseq[((size_t)b*256+255)*128 + tid];
    write_feat7(featA + ((size_t)(b*128+tid))*7, cv);
  }
}

// ---------------- KAN i-chunk partial, z-merged pair (mu/sd or mc/sc) ----------------
__global__ __launch_bounds__(256) void kanp2_kernel(
    const float* __restrict__ feat,
    const float* __restrict__ W1a, const float* __restrict__ B1a, const float* __restrict__ W2a,
    const float* __restrict__ W1b, const float* __restrict__ B1b, const float* __restrict__ W2b,
    int din, int dout, float* __restrict__ partial, int pstride)
{
  __shared__ float feat_s[32*225];
  __shared__ float red[8][32];
  int z = blockIdx.z;
  const float* W1 = z ? W1b : W1a;
  const float* B1 = z ? B1b : B1a;
  const float* W2 = z ? W2b : W2a;
  partial += (size_t)z * pstride;
  int j = blockIdx.x, ic = blockIdx.y;
  int i0 = ic*32;
  int tid = threadIdx.x;
  int b = tid & 31, hg = tid >> 5;
  for(int q=tid; q<1792; q+=256){
    int br = q/56, qq = q - br*56;
    float4 v = *(const float4*)(feat + ((size_t)br*din + i0)*7 + qq*4);
    float* d = &feat_s[br*225 + qq*4];
    d[0]=v.x; d[1]=v.y; d[2]=v.z; d[3]=v.w;
  }
  __syncthreads();
  float acc = 0.f;
  const float* fb = &feat_s[b*225];
  for(int ii=0; ii<32; ii++){
    int i = i0 + ii;
    size_t hbase = ((size_t)i*dout + j)*32 + hg*4;
    const float4* w1p = (const float4*)(W1 + ((size_t)i*dout + j)*224 + hg*28);
    float w1a[28];
    #pragma unroll
    for(int q=0;q<7;q++) *(float4*)&w1a[q*4] = w1p[q];
    float4 b1v = *(const float4*)(B1 + hbase);
    float4 w2v = *(const float4*)(W2 + hbase);
    float f[7];
    #pragma unroll
    for(int q=0;q<7;q++) f[q] = fb[ii*7+q];
    float b1a[4] = {b1v.x, b1v.y, b1v.z, b1v.w};
    float w2a[4] = {w2v.x, w2v.y, w2v.z, w2v.w};
    #pragma unroll
    for(int hh=0;hh<4;hh++){
      float hv = b1a[hh];
      #pragma unroll
      for(int q=0;q<7;q++) hv = fmaf(f[q], w1a[hh*7+q], hv);
      float sv = hv / (1.f + __expf(-hv));   // silu
      acc = fmaf(sv, w2a[hh], acc);
    }
  }
  red[hg][b] = acc;
  __syncthreads();
  if(tid < 32){
    float s = 0.f;
    #pragma unroll
    for(int q=0;q<8;q++) s += red[q][tid];
    partial[((size_t)ic*32 + tid)*dout + j] = s;
  }
}

// ---------------- generic KAN i-chunk partial (fc path, grid (10,8)) ----------------
__global__ __launch_bounds__(256) void kanp_kernel(
    const float* __restrict__ feat, const float* __restrict__ W1,
    const float* __restrict__ B1, const float* __restrict__ W2,
    int din, int dout, float* __restrict__ partial)
{
  __shared__ float feat_s[32*225];
  __shared__ float red[8][32];
  int j = blockIdx.x, ic = blockIdx.y;
  int i0 = ic*32;
  int tid = threadIdx.x;
  int b = tid & 31, hg = tid >> 5;
  for(int q=tid; q<1792; q+=256){
    int br = q/56, qq = q - br*56;
    float4 v = *(const float4*)(feat + ((size_t)br*din + i0)*7 + qq*4);
    float* d = &feat_s[br*225 + qq*4];
    d[0]=v.x; d[1]=v.y; d[2]=v.z; d[3]=v.w;
  }
  __syncthreads();
  float acc = 0.f;
  const float* fb = &feat_s[b*225];
  for(int ii=0; ii<32; ii++){
    int i = i0 + ii;
    size_t hbase = ((size_t)i*dout + j)*32 + hg*4;
    const float4* w1p = (const float4*)(W1 + ((size_t)i*dout + j)*224 + hg*28);
    float w1a[28];
    #pragma unroll
    for(int q=0;q<7;q++) *(float4*)&w1a[q*4] = w1p[q];
    float4 b1v = *(const float4*)(B1 + hbase);
    float4 w2v = *(const float4*)(W2 + hbase);
    float f[7];
    #pragma unroll
    for(int q=0;q<7;q++) f[q] = fb[ii*7+q];
    float b1a[4] = {b1v.x, b1v.y, b1v.z, b1v.w};
    float w2a[4] = {w2v.x, w2v.y, w2v.z, w2v.w};
    #pragma unroll
    for(int hh=0;hh<4;hh++){
      float hv = b1a[hh];
      #pragma unroll
      for(int q=0;q<7;q++) hv = fmaf(f[q], w1a[hh*7+q], hv);
      float sv = hv / (1.f + __expf(-hv));
      acc = fmaf(sv, w2a[hh], acc);
    }
  }
  red[hg][b] = acc;
  __syncthreads();
  if(tid < 32){
    float s = 0.f;
    #pragma unroll
    for(int q=0;q<8;q++) s += red[q][tid];
    partial[((size_t)ic*32 + tid)*dout + j] = s;
  }
}

// ---------------- KAN reduce (fc path) ----------------
__global__ __launch_bounds__(256) void kanr_kernel(
    const float* __restrict__ partial, const float* __restrict__ b2s,
    int NI, int dout, float* __restrict__ outp)
{
  int idx = blockIdx.x*256 + threadIdx.x;
  if(idx >= 32*dout) return;
  int b = idx / dout, j = idx - b*dout;
  float s = b2s[j];
  for(int ic=0; ic<NI; ic++) s += partial[((size_t)ic*32 + b)*dout + j];
  outp[idx] = s;
}

// ---------------- fused kanr(mu)+kanr(sd)+zmix+featB ----------------
__global__ __launch_bounds__(256) void kanrz_kernel(
    const float* __restrict__ kp, const float* __restrict__ b2s,
    const float* __restrict__ eps1, const float* __restrict__ last, float* __restrict__ featB)
{
  int idx = blockIdx.x*256 + threadIdx.x;
  if(idx >= 4096) return;
  int b = idx >> 7, j = idx & 127;
  float mu = b2s[j], sd = b2s[128+j];
  #pragma unroll
  for(int ic=0; ic<4; ic++){
    mu += kp[((size_t)ic*32 + b)*128 + j];
    sd += kp[16384 + ((size_t)ic*32 + b)*128 + j];
  }
  float z = mu + softplusf(sd - 5.f)*eps1[idx];
  float lv = last[idx];
  write_feat7(featB + ((size_t)(b*256 + j))*7, lv);
  write_feat7(featB + ((size_t)(b*256 + 128 + j))*7, z);
}

// ---------------- fused kanr(mc)+kanr(sc)+xall+featC ----------------
__global__ __launch_bounds__(256) void kanrx_kernel(
    const float* __restrict__ kp, const float* __restrict__ b2s,
    const float* __restrict__ eps2, const float* __restrict__ x2f, float* __restrict__ featC)
{
  int idx = blockIdx.x*256 + threadIdx.x;
  if(idx >= 4096) return;
  int b = idx >> 7, j = idx & 127;
  float mu = b2s[256+j], sd = b2s[384+j];
  #pragma unroll
  for(int ic=0; ic<8; ic++){
    mu += kp[((size_t)ic*32 + b)*128 + j];
    sd += kp[32768 + ((size_t)ic*32 + b)*128 + j];
  }
  float v0 = mu + softplusf(sd - 5.f)*eps2[idx];
  float v1 = x2f[idx];
  write_feat7(featC + ((size_t)(b*256 + j))*7, v0);
  write_feat7(featC + ((size_t)(b*256 + 128 + j))*7, v1);
}

// ---------------- launch ----------------
extern "C" void kernel_launch(void* const* d_in, const int* in_sizes, int n_in,
                              void* d_out, int out_size, void* d_ws, size_t ws_size,
                              hipStream_t stream)
{
  const float* x    = (const float*)d_in[0];
  const float* we1  = (const float*)d_in[1];
  const float* be1  = (const float*)d_in[2];
  const float* e1g  = (const float*)d_in[3];
  const float* e1b  = (const float*)d_in[4];
  const float* e1m  = (const float*)d_in[5];
  const float* e1v  = (const float*)d_in[6];
  const float* we2  = (const float*)d_in[7];
  const float* be2  = (const float*)d_in[8];
  const float* e2g  = (const float*)d_in[9];
  const float* e2b  = (const float*)d_in[10];
  const float* e2m  = (const float*)d_in[11];
  const float* e2v  = (const float*)d_in[12];
  const float* wih  = (const float*)d_in[13];
  const float* whh  = (const float*)d_in[14];
  const float* bih  = (const float*)d_in[15];
  const float* bhh  = (const float*)d_in[16];
  const float* muW1 = (const float*)d_in[17];
  const float* muW2 = (const float*)d_in[18];
  const float* muB1 = (const float*)d_in[19];
  const float* muB2 = (const float*)d_in[20];
  const float* sdW1 = (const float*)d_in[21];
  const float* sdW2 = (const float*)d_in[22];
  const float* sdB1 = (const float*)d_in[23];
  const float* sdB2 = (const float*)d_in[24];
  const float* mcW1 = (const float*)d_in[25];
  const float* mcW2 = (const float*)d_in[26];
  const float* mcB1 = (const float*)d_in[27];
  const float* mcB2 = (const float*)d_in[28];
  const float* scW1 = (const float*)d_in[29];
  const float* scW2 = (const float*)d_in[30];
  const float* scB1 = (const float*)d_in[31];
  const float* scB2 = (const float*)d_in[32];
  const float* fcW1 = (const float*)d_in[33];
  const float* fcW2 = (const float*)d_in[34];
  const float* fcB1 = (const float*)d_in[35];
  const float* fcB2 = (const float*)d_in[36];
  const float* wc1  = (const float*)d_in[37];
  const float* bc1  = (const float*)d_in[38];
  const float* c1g  = (const float*)d_in[39];
  const float* c1b  = (const float*)d_in[40];
  const float* c1m  = (const float*)d_in[41];
  const float* c1v  = (const float*)d_in[42];
  const float* se1w1= (const float*)d_in[43];
  const float* se1w2= (const float*)d_in[44];
  const float* wc2  = (const float*)d_in[45];
  const float* bc2  = (const float*)d_in[46];
  const float* c2g  = (const float*)d_in[47];
  const float* c2b  = (const float*)d_in[48];
  const float* c2m  = (const float*)d_in[49];
  const float* c2v  = (const float*)d_in[50];
  const float* se2w1= (const float*)d_in[51];
  const float* se2w2= (const float*)d_in[52];
  const float* wc3  = (const float*)d_in[53];
  const float* bc3  = (const float*)d_in[54];
  const float* c3g  = (const float*)d_in[55];
  const float* c3b  = (const float*)d_in[56];
  const float* c3m  = (const float*)d_in[57];
  const float* c3v  = (const float*)d_in[58];
  const float* eps1 = (const float*)d_in[59];
  const float* eps2 = (const float*)d_in[60];

  float* ws = (float*)d_ws;
  float* kp   = ws + OFF_KP;   // mu/sd partials (16384 each); fc partials reuse +0
  float* kp2  = ws + OFF_GX;   // mc/sc partials (32768 each) - GX dead after lstm
  float* b2s  = ws + OFF_B2S;

  prep_kernel<<<3984, 256, 0, stream>>>(we1, be1, e1g,e1b,e1m,e1v,
      we2, be2,e2g,e2b,e2m,e2v, wih,whh,bih,bhh,
      bc1,c1g,c1b,c1m,c1v, bc2,c2g,c2b,c2m,c2v, bc3,c3g,c3b,c3m,c3v,
      muB2, sdB2, mcB2, scB2, fcB2, wc2, wc3, ws);

  encoder_kernel<<<256, 256, 0, stream>>>(x, ws+OFF_W1F, ws+OFF_B1F,
      ws+OFF_S2E, ws+OFF_B2E, (const bf16*)(ws+OFF_WE2B), ws+OFF_XSRC);

  gates_kernel<<<256, 256, 0, stream>>>(ws+OFF_XSRC, ws+OFF_WIHT, ws+OFF_BIASG, ws+OFF_GX);

  // mega: lstm (blocks 0-31) + full conv/SE branch (blocks 32-63) overlapped
  lstm_conv_kernel<<<64, 256, 0, stream>>>(ws+OFF_GX, ws+OFF_WHHT, ws+OFF_HSEQ,
      x, wc1, ws+OFF_WC2P, ws+OFF_WC3P,
      ws+OFF_EPI1S, ws+OFF_EPI1B, ws+OFF_EPI2S, ws+OFF_EPI2B, ws+OFF_EPI3S, ws+OFF_EPI3B,
      se1w1, se1w2, se2w1, se2w2, ws+OFF_X2F);

  pc_kernel<<<256, 256, 0, stream>>>(ws+OFF_HSEQ, ws+OFF_PCOL, ws+OFF_CCOL);
  cutcorr_kernel<<<32, 256, 0, stream>>>(ws+OFF_PCOL, ws+OFF_CCOL, ws+OFF_HSEQ,
      ws+OFF_LAST, ws+OFF_FEATA, (int*)(ws+OFF_CUTS));

  kanp2_kernel<<<dim3(128,4,2), 256, 0, stream>>>(ws+OFF_FEATA,
      muW1, muB1, muW2, sdW1, sdB1, sdW2, 128, 128, kp, 16384);
  kanrz_kernel<<<16, 256, 0, stream>>>(kp, b2s, eps1, ws+OFF_LAST, ws+OFF_FEATB);

  kanp2_kernel<<<dim3(128,8,2), 256, 0, stream>>>(ws+OFF_FEATB,
      mcW1, mcB1, mcW2, scW1, scB1, scW2, 256, 128, kp2, 32768);
  kanrx_kernel<<<16, 256, 0, stream>>>(kp2, b2s, eps2, ws+OFF_X2F, ws+OFF_FEATC);

  // fc KAN: parallel over ic (80 blocks) + tiny reduce -- R10's 10-block single-pass
  // version serialized the ic loop on 10 CUs and cost ~+80us.
  kanp_kernel<<<dim3(10,8), 256, 0, stream>>>(ws+OFF_FEATC, fcW1, fcB1, fcW2, 256, 10, kp);
  kanr_kernel<<<2, 256, 0, stream>>>(kp, b2s+512, 8, 10, (float*)d_out);
}